// Round 4
// baseline (733.136 us; speedup 1.0000x reference)
//
#include <hip/hip_runtime.h>
#include <math.h>

#define N_B 64
#define T_LEN 1024
#define IN_D 4
#define CH 5
#define SIG 780
#define KP 800           // padded K for f16 planes
#define NPAD 896         // padded N for W planes
#define SEG_LEN 16
#define N_SEG 64
// level offsets: L1:0, L2:5, L3:30, L4:155
#define SC_L1 1.0f
#define SC_L2 0.25f
#define SC_L3 0.0625f
#define SC_L4 0.015625f

typedef _Float16 f16x8 __attribute__((ext_vector_type(8)));
typedef float f32x4 __attribute__((ext_vector_type(4)));

typedef __attribute__((address_space(1))) const void* as1cp;
typedef __attribute__((address_space(3))) void* as3p;

__device__ __forceinline__ float fast_tanh(float x) {
  float ax = fabsf(x);
  float e = __expf(-2.0f * ax);
  float r = (1.0f - e) * __builtin_amdgcn_rcpf(1.0f + e);
  return copysignf(r, x);
}

__device__ __forceinline__ float sel5(float d0, float d1, float d2, float d3,
                                      float d4, int i) {
  float r = d0;
  r = (i == 1) ? d1 : r;
  r = (i == 2) ? d2 : r;
  r = (i == 3) ? d3 : r;
  r = (i == 4) ? d4 : r;
  return r;
}

// ======================= wave-synchronous signature ==========================
// Shared per-step machinery: one wave (64 lanes). L4 state x=lane*10+q in
// registers (only its own lane ever reads/writes it); L1-L3 (155) in LDS.

// ---------------- phase A: per-segment signatures (conv fused) ----------------
__global__ __launch_bounds__(64) void seg_wave(
    const float* __restrict__ batch,
    const float* __restrict__ conv_w,
    const float* __restrict__ conv_b,
    float* __restrict__ P) {
  int s = blockIdx.x;
  int n = blockIdx.y;
  int lane = threadIdx.x;

  __shared__ float S123[160];           // [0,5) L1, [5,30) L2, [30,155) L3 (+pad)
  __shared__ float bc[85];
  __shared__ float dsh[SEG_LEN][CH];

  for (int i = lane; i < 160; i += 64) S123[i] = 0.0f;
#pragma unroll
  for (int p = 0; p < 2; ++p) {
    int e = lane + p * 64;
    if (e < (SEG_LEN + 1) * CH) {
      int r = s * SEG_LEN - 1 + e / CH, ch = e % CH;
      float v = 0.0f;
      if (r >= 0) {
        const float* a = batch + ((size_t)n * T_LEN + r) * IN_D;
        const float* w = conv_w + ch * CH;
        v = conv_b[ch];
        v = fmaf(a[0], w[0], v);
        v = fmaf(a[1], w[1], v);
        v = fmaf(a[2], w[2], v);
        v = fmaf(a[3], w[3], v);
        v = fmaf((float)(r + 1) * (1.0f / T_LEN), w[4], v);
      }
      bc[e] = v;
    }
  }
  __syncthreads();
#pragma unroll
  for (int p = 0; p < 2; ++p) {
    int e = lane + p * 64;
    if (e < SEG_LEN * CH) dsh[e / CH][e % CH] = bc[e + CH] - bc[e];
  }
  __syncthreads();

  // per-lane constant setup
  const int xb = lane * 10;
  const int a_lo = xb / 125, a_hi = (xb + 9) / 125;
  const int s2_lo = xb / 25, s2_hi = (xb + 9) / 25;
  const int s3_lo = 2 * lane, s3_hi = 2 * lane + 1;
  const int b_lo = s2_lo % 5, b_hi = s2_hi % 5;
  const int c_lo = s3_lo % 5, c_hi = s3_hi % 5;
  const int q_a = a_lo * 125 + 125 - xb;
  const int q_b = s2_lo * 25 + 25 - xb;
  const int y0 = lane, y1 = lane + 64;
  const bool hy0 = (y0 < 125), hy1 = (y1 < 125);
  const int y0a = y0 / 25, y0s = y0 / 5, y0b = y0s % 5, y0c = y0 % 5;
  const int y1a = y1 / 25, y1s = y1 / 5, y1b = y1s % 5, y1c = y1 % 5;
  const bool hz = (lane < 25);
  const int za = lane / 5, zb = lane % 5;
  const bool h1 = (lane < 5);

  float S4r[10];
#pragma unroll
  for (int q = 0; q < 10; ++q) S4r[q] = 0.0f;

  for (int j = 0; j < SEG_LEN; ++j) {
    float dr0 = dsh[j][0], dr1 = dsh[j][1], dr2 = dsh[j][2], dr3 = dsh[j][3],
          dr4 = dsh[j][4];
    float drA[5] = {dr0, dr1, dr2, dr3, dr4};
    float da_l = sel5(dr0, dr1, dr2, dr3, dr4, a_lo);
    float da_h = sel5(dr0, dr1, dr2, dr3, dr4, a_hi);
    float db_l = sel5(dr0, dr1, dr2, dr3, dr4, b_lo);
    float db_h = sel5(dr0, dr1, dr2, dr3, dr4, b_hi);
    float dc_l = sel5(dr0, dr1, dr2, dr3, dr4, c_lo);
    float dc_h = sel5(dr0, dr1, dr2, dr3, dr4, c_hi);
    float s1_l = S123[a_lo], s1_h = S123[a_hi];
    float s2v_l = S123[5 + s2_lo], s2v_h = S123[5 + s2_hi];
    float s3v_l = S123[30 + s3_lo], s3v_h = S123[30 + s3_hi];

#pragma unroll
    for (int q = 0; q < 10; ++q) {
      bool ua = (q >= q_a), ub = (q >= q_b);
      float s1 = ua ? s1_h : s1_l, da = ua ? da_h : da_l;
      float s2v = ub ? s2v_h : s2v_l, db = ub ? db_h : db_l;
      float s3v = (q < 5) ? s3v_l : s3v_h;
      float dc = (q < 5) ? dc_l : dc_h;
      float dd = drA[q % 5];
      float tH = fmaf(0.25f, da, s1);
      tH = fmaf((1.0f / 3.0f) * db, tH, s2v);
      tH = fmaf(0.5f * dc, tH, s3v);
      S4r[q] = fmaf(dd, tH, S4r[q]);
    }

    float n3_0 = 0.f, n3_1 = 0.f, n2 = 0.f, n1 = 0.f;
    if (hy0) {
      float tH = fmaf((1.0f / 3.0f), drA[0] * 0.f + dsh[j][y0a], S123[y0a]);
      tH = fmaf(0.5f * dsh[j][y0b], tH, S123[5 + y0s]);
      n3_0 = fmaf(dsh[j][y0c], tH, S123[30 + y0]);
    }
    if (hy1) {
      float tH = fmaf((1.0f / 3.0f), dsh[j][y1a], S123[y1a]);
      tH = fmaf(0.5f * dsh[j][y1b], tH, S123[5 + y1s]);
      n3_1 = fmaf(dsh[j][y1c], tH, S123[30 + y1]);
    }
    if (hz) {
      float tH = fmaf(0.5f, dsh[j][za], S123[za]);
      n2 = fmaf(dsh[j][zb], tH, S123[5 + lane]);
    }
    if (h1) n1 = S123[lane] + dsh[j][lane];
    __syncthreads();
    if (hy0) S123[30 + y0] = n3_0;
    if (hy1) S123[30 + y1] = n3_1;
    if (hz) S123[5 + lane] = n2;
    if (h1) S123[lane] = n1;
    __syncthreads();
  }

  float* Pr = P + ((size_t)n * N_SEG + s) * SIG;
  for (int i = lane; i < 155; i += 64) Pr[i] = S123[i];
#pragma unroll
  for (int q = 0; q < 10; ++q) {
    int x = xb + q;
    if (x < 625) Pr[155 + x] = S4r[q];
  }
}

// ---------------- phase B: sequential prefix over segments ----------------
__global__ __launch_bounds__(640) void prefix_kernel(float* __restrict__ P) {
  int n = blockIdx.x;
  int tid = threadIdx.x;
  __shared__ float A[SIG];
  __shared__ float Bs[SIG];

  float* Pn = P + (size_t)n * N_SEG * SIG;
  for (int i = tid; i < SIG; i += 640) A[i] = Pn[i];
  int i0 = tid, i1 = tid + 640;
  float r0 = 0.f, r1 = 0.f;
  if (i0 < SIG) r0 = Pn[SIG + i0];
  if (i1 < SIG) r1 = Pn[SIG + i1];

  const int e4 = tid;
  const int q4a = e4 / 125, r125 = e4 % 125, r25 = e4 % 25, r5 = e4 % 5;
  const int e4d5 = e4 / 5, e4d25 = e4 / 25;
  const int e3 = tid;
  const int e3a = e3 / 25, e3r25 = e3 % 25, e3r5 = e3 % 5, e3d5 = e3 / 5;
  const int e2 = tid - 125;
  const int e1 = tid - 150;

  for (int s = 1; s < N_SEG; ++s) {
    if (i0 < SIG) Bs[i0] = r0;
    if (i1 < SIG) Bs[i1] = r1;
    __syncthreads();
    if (s + 1 < N_SEG) {
      const float* Pnx = Pn + (size_t)(s + 1) * SIG;
      if (i0 < SIG) r0 = Pnx[i0];
      if (i1 < SIG) r1 = Pnx[i1];
    }
    float v4 = 0.f, v3 = 0.f, v2 = 0.f, v1 = 0.f;
    if (tid < 625) {
      v4 = A[155 + e4] + Bs[155 + e4];
      v4 = fmaf(A[30 + e4d5], Bs[r5], v4);
      v4 = fmaf(A[5 + e4d25], Bs[5 + r25], v4);
      v4 = fmaf(A[q4a], Bs[30 + r125], v4);
    }
    if (tid < 125) {
      v3 = A[30 + e3] + Bs[30 + e3];
      v3 = fmaf(A[5 + e3d5], Bs[e3r5], v3);
      v3 = fmaf(A[e3a], Bs[5 + e3r25], v3);
    } else if (tid < 150) {
      v2 = A[5 + e2] + Bs[5 + e2];
      v2 = fmaf(A[e2 / 5], Bs[e2 % 5], v2);
    } else if (tid < 155) {
      v1 = A[e1] + Bs[e1];
    }
    __syncthreads();
    float* Po = Pn + (size_t)s * SIG;
    if (tid < 625) { A[155 + e4] = v4; Po[155 + e4] = v4; }
    if (tid < 125) { A[30 + e3] = v3; Po[30 + e3] = v3; }
    else if (tid < 150) { A[5 + e2] = v2; Po[5 + e2] = v2; }
    else if (tid < 155) { A[e1] = v1; Po[e1] = v1; }
  }
}

// ---------------- phase C: stream + emit f16 hi/lo planes ----------------
__global__ __launch_bounds__(64) void emit_wave(
    const float* __restrict__ batch,
    const float* __restrict__ conv_w,
    const float* __restrict__ conv_b,
    const float* __restrict__ P,
    _Float16* __restrict__ c1,
    _Float16* __restrict__ c2) {
  int s = blockIdx.x;
  int n = blockIdx.y;
  int lane = threadIdx.x;

  __shared__ float S123[160];
  __shared__ float bc[85];
  __shared__ float dsh[SEG_LEN][CH];
  __shared__ __align__(16) _Float16 row1[KP];
  __shared__ __align__(16) _Float16 row2[KP];

  const int xb = lane * 10;
  float S4r[10];
  if (s == 0) {
    for (int i = lane; i < 160; i += 64) S123[i] = 0.0f;
#pragma unroll
    for (int q = 0; q < 10; ++q) S4r[q] = 0.0f;
  } else {
    const float* Pr = P + ((size_t)n * N_SEG + (s - 1)) * SIG;
    for (int i = lane; i < 155; i += 64) S123[i] = Pr[i];
    if (lane < 5) S123[155 + lane] = 0.0f;
#pragma unroll
    for (int q = 0; q < 10; ++q) {
      int x = xb + q;
      S4r[q] = (x < 625) ? Pr[155 + x] : 0.0f;
    }
  }
#pragma unroll
  for (int p = 0; p < 2; ++p) {
    int e = lane + p * 64;
    if (e < (SEG_LEN + 1) * CH) {
      int r = s * SEG_LEN - 1 + e / CH, ch = e % CH;
      float v = 0.0f;
      if (r >= 0) {
        const float* a = batch + ((size_t)n * T_LEN + r) * IN_D;
        const float* w = conv_w + ch * CH;
        v = conv_b[ch];
        v = fmaf(a[0], w[0], v);
        v = fmaf(a[1], w[1], v);
        v = fmaf(a[2], w[2], v);
        v = fmaf(a[3], w[3], v);
        v = fmaf((float)(r + 1) * (1.0f / T_LEN), w[4], v);
      }
      bc[e] = v;
    }
  }
  if (lane < KP - SIG) {
    row1[SIG + lane] = (_Float16)0.0f;
    row2[SIG + lane] = (_Float16)0.0f;
  }
  __syncthreads();
#pragma unroll
  for (int p = 0; p < 2; ++p) {
    int e = lane + p * 64;
    if (e < SEG_LEN * CH) dsh[e / CH][e % CH] = bc[e + CH] - bc[e];
  }
  __syncthreads();

  const int a_lo = xb / 125, a_hi = (xb + 9) / 125;
  const int s2_lo = xb / 25, s2_hi = (xb + 9) / 25;
  const int s3_lo = 2 * lane, s3_hi = 2 * lane + 1;
  const int b_lo = s2_lo % 5, b_hi = s2_hi % 5;
  const int c_lo = s3_lo % 5, c_hi = s3_hi % 5;
  const int q_a = a_lo * 125 + 125 - xb;
  const int q_b = s2_lo * 25 + 25 - xb;
  const int y0 = lane, y1 = lane + 64;
  const bool hy0 = (y0 < 125), hy1 = (y1 < 125);
  const int y0a = y0 / 25, y0s = y0 / 5, y0b = y0s % 5, y0c = y0 % 5;
  const int y1a = y1 / 25, y1s = y1 / 5, y1b = y1s % 5, y1c = y1 % 5;
  const bool hz = (lane < 25);
  const int za = lane / 5, zb = lane % 5;
  const bool h1 = (lane < 5);

  for (int j = 0; j < SEG_LEN; ++j) {
    int t = s * SEG_LEN + j;
    float zf = (t == 0) ? 0.0f : 1.0f;
    float dr0 = dsh[j][0], dr1 = dsh[j][1], dr2 = dsh[j][2], dr3 = dsh[j][3],
          dr4 = dsh[j][4];
    float drA[5] = {dr0, dr1, dr2, dr3, dr4};
    float da_l = sel5(dr0, dr1, dr2, dr3, dr4, a_lo);
    float da_h = sel5(dr0, dr1, dr2, dr3, dr4, a_hi);
    float db_l = sel5(dr0, dr1, dr2, dr3, dr4, b_lo);
    float db_h = sel5(dr0, dr1, dr2, dr3, dr4, b_hi);
    float dc_l = sel5(dr0, dr1, dr2, dr3, dr4, c_lo);
    float dc_h = sel5(dr0, dr1, dr2, dr3, dr4, c_hi);
    float s1_l = S123[a_lo], s1_h = S123[a_hi];
    float s2v_l = S123[5 + s2_lo], s2v_h = S123[5 + s2_hi];
    float s3v_l = S123[30 + s3_lo], s3v_h = S123[30 + s3_hi];

#pragma unroll
    for (int q = 0; q < 10; ++q) {
      bool ua = (q >= q_a), ub = (q >= q_b);
      float s1 = ua ? s1_h : s1_l, da = ua ? da_h : da_l;
      float s2v = ub ? s2v_h : s2v_l, db = ub ? db_h : db_l;
      float s3v = (q < 5) ? s3v_l : s3v_h;
      float dc = (q < 5) ? dc_l : dc_h;
      float dd = drA[q % 5];
      float tH = fmaf(0.25f, da, s1);
      tH = fmaf((1.0f / 3.0f) * db, tH, s2v);
      tH = fmaf(0.5f * dc, tH, s3v);
      S4r[q] = fmaf(dd, tH, S4r[q]);
    }

    float n3_0 = 0.f, n3_1 = 0.f, n2 = 0.f, n1 = 0.f;
    if (hy0) {
      float tH = fmaf((1.0f / 3.0f), dsh[j][y0a], S123[y0a]);
      tH = fmaf(0.5f * dsh[j][y0b], tH, S123[5 + y0s]);
      n3_0 = fmaf(dsh[j][y0c], tH, S123[30 + y0]);
    }
    if (hy1) {
      float tH = fmaf((1.0f / 3.0f), dsh[j][y1a], S123[y1a]);
      tH = fmaf(0.5f * dsh[j][y1b], tH, S123[5 + y1s]);
      n3_1 = fmaf(dsh[j][y1c], tH, S123[30 + y1]);
    }
    if (hz) {
      float tH = fmaf(0.5f, dsh[j][za], S123[za]);
      n2 = fmaf(dsh[j][zb], tH, S123[5 + lane]);
    }
    if (h1) n1 = S123[lane] + dsh[j][lane];
    __syncthreads();

    // commit + build scaled f16 row
    if (hy0) S123[30 + y0] = n3_0;
    if (hy1) S123[30 + y1] = n3_1;
    if (hz) S123[5 + lane] = n2;
    if (h1) S123[lane] = n1;
#pragma unroll
    for (int q = 0; q < 10; ++q) {
      int x = xb + q;
      if (x < 625) {
        float v = S4r[q] * (SC_L4 * zf);
        _Float16 h = (_Float16)v;
        row1[155 + x] = h;
        row2[155 + x] = (_Float16)(v - (float)h);
      }
    }
    if (hy0) {
      float v = n3_0 * (SC_L3 * zf);
      _Float16 h = (_Float16)v;
      row1[30 + y0] = h; row2[30 + y0] = (_Float16)(v - (float)h);
    }
    if (hy1) {
      float v = n3_1 * (SC_L3 * zf);
      _Float16 h = (_Float16)v;
      row1[30 + y1] = h; row2[30 + y1] = (_Float16)(v - (float)h);
    }
    if (hz) {
      float v = n2 * (SC_L2 * zf);
      _Float16 h = (_Float16)v;
      row1[5 + lane] = h; row2[5 + lane] = (_Float16)(v - (float)h);
    }
    if (h1) {
      float v = n1 * (SC_L1 * zf);
      _Float16 h = (_Float16)v;
      row1[lane] = h; row2[lane] = (_Float16)(v - (float)h);
    }
    __syncthreads();

    // coalesced 16B-chunk stores (100 chunks per plane)
    size_t base = ((size_t)n * T_LEN + t) * KP;
    *(float4*)(c1 + base + lane * 8) = *(const float4*)&row1[lane * 8];
    *(float4*)(c2 + base + lane * 8) = *(const float4*)&row2[lane * 8];
    if (lane < 36) {
      *(float4*)(c1 + base + (64 + lane) * 8) = *(const float4*)&row1[(64 + lane) * 8];
      *(float4*)(c2 + base + (64 + lane) * 8) = *(const float4*)&row2[(64 + lane) * 8];
    }
  }
}

// ---------------- W plane conversion (scaled, padded to 896x800) -------------
__global__ __launch_bounds__(256) void wconv_kernel(
    const float* __restrict__ W,
    _Float16* __restrict__ w1,
    _Float16* __restrict__ w2) {
  int idx = blockIdx.x * blockDim.x + threadIdx.x;
  if (idx >= NPAD * KP) return;
  int nn = idx / KP, k = idx % KP;
  float v = 0.0f;
  if (nn < SIG && k < SIG) {
    float sc = (k < 5) ? 1.0f : (k < 30) ? 4.0f : (k < 155) ? 16.0f : 64.0f;
    v = W[(size_t)nn * SIG + k] * sc;
  }
  _Float16 h = (_Float16)v;
  w1[idx] = h;
  w2[idx] = (_Float16)(v - (float)h);
}

// ---------------- persistent-m MFMA GEMM ------------------------------------
// 512 blocks; each owns a 128-row A-strip (L2-resident after first n-pass)
// and loops over 7 n-tiles. Per n-tile: double-buffered k-loop, 3 f16
// products (hi*hi, hi*lo, lo*hi) into fp32 acc, fast-tanh epilogue via LDS
// transpose + float4 stores.
__global__ __launch_bounds__(256) void gemm_mfma(
    const _Float16* __restrict__ A1p, const _Float16* __restrict__ A2p,
    const _Float16* __restrict__ B1p, const _Float16* __restrict__ B2p,
    const float* __restrict__ bias, float* __restrict__ out) {
  __shared__ _Float16 Al[2][2][128 * 32];  // [buf][plane]
  __shared__ _Float16 Bl[2][2][128 * 32];

  int tid = threadIdx.x;
  int lane = tid & 63, wid = tid >> 6;
  int wm = wid >> 1, wn = wid & 1;
  int m0 = blockIdx.x * 128;

  int sr = lane >> 2, scn = lane & 3;
  int swst = (sr ^ (sr >> 2)) & 3;
  int qg = scn ^ swst;
  int fr = lane & 15, fq = lane >> 4;
  int swf = (fr ^ (fr >> 2)) & 3;
  int fchunk = fq ^ swf;

  auto stage = [&](int n0, int kb, int buf) {
    int k0 = kb * 32;
#pragma unroll
    for (int i = 0; i < 2; ++i) {
      int rloc = wid * 16 + i * 64 + sr;
      size_t gA = (size_t)(m0 + rloc) * KP + k0 + qg * 8;
      size_t gB = (size_t)(n0 + rloc) * KP + k0 + qg * 8;
      int lb = (wid * 16 + i * 64) * 32;
      __builtin_amdgcn_global_load_lds((as1cp)(A1p + gA), (as3p)(&Al[buf][0][lb]), 16, 0, 0);
      __builtin_amdgcn_global_load_lds((as1cp)(A2p + gA), (as3p)(&Al[buf][1][lb]), 16, 0, 0);
      __builtin_amdgcn_global_load_lds((as1cp)(B1p + gB), (as3p)(&Bl[buf][0][lb]), 16, 0, 0);
      __builtin_amdgcn_global_load_lds((as1cp)(B2p + gB), (as3p)(&Bl[buf][1][lb]), 16, 0, 0);
    }
  };

  for (int nt = 0; nt < 7; ++nt) {
    int n0 = nt * 128;

    f32x4 acc[4][4];
#pragma unroll
    for (int i = 0; i < 4; ++i)
#pragma unroll
      for (int j = 0; j < 4; ++j) acc[i][j] = (f32x4){0.f, 0.f, 0.f, 0.f};

    stage(n0, 0, 0);
    for (int kb = 0; kb < 25; ++kb) {
      int cur = kb & 1;
      __syncthreads();  // drains vmcnt(0): buf[cur] ready; buf[cur^1] free
      f16x8 a1[4], a2[4], b1[4], b2[4];
#pragma unroll
      for (int tm = 0; tm < 4; ++tm) {
        int off = (wm * 64 + tm * 16 + fr) * 32 + fchunk * 8;
        a1[tm] = *(const f16x8*)&Al[cur][0][off];
        a2[tm] = *(const f16x8*)&Al[cur][1][off];
      }
#pragma unroll
      for (int tn = 0; tn < 4; ++tn) {
        int off = (wn * 64 + tn * 16 + fr) * 32 + fchunk * 8;
        b1[tn] = *(const f16x8*)&Bl[cur][0][off];
        b2[tn] = *(const f16x8*)&Bl[cur][1][off];
      }
      if (kb < 24) stage(n0, kb + 1, cur ^ 1);
#pragma unroll
      for (int tm = 0; tm < 4; ++tm)
#pragma unroll
        for (int tn = 0; tn < 4; ++tn) {
          acc[tm][tn] = __builtin_amdgcn_mfma_f32_16x16x32_f16(a1[tm], b1[tn], acc[tm][tn], 0, 0, 0);
          acc[tm][tn] = __builtin_amdgcn_mfma_f32_16x16x32_f16(a1[tm], b2[tn], acc[tm][tn], 0, 0, 0);
          acc[tm][tn] = __builtin_amdgcn_mfma_f32_16x16x32_f16(a2[tm], b1[tn], acc[tm][tn], 0, 0, 0);
        }
    }
    __syncthreads();  // frag reads done; LDS reusable for epilogue

    // epilogue: bias + fast tanh, per-wave LDS transpose, float4 stores
    float* ep = (float*)((wid < 2) ? (void*)&Al[0][0][0] : (void*)&Bl[0][0][0]);
    ep += (wid & 1) * 4096;

    float bv[4];
#pragma unroll
    for (int tn = 0; tn < 4; ++tn) {
      int nn = n0 + wn * 64 + tn * 16 + fr;
      bv[tn] = (nn < SIG) ? bias[nn] : 0.0f;
    }
#pragma unroll
    for (int h = 0; h < 2; ++h) {
#pragma unroll
      for (int tm2 = 0; tm2 < 2; ++tm2) {
        int tm = h * 2 + tm2;
#pragma unroll
        for (int tn = 0; tn < 4; ++tn) {
#pragma unroll
          for (int r = 0; r < 4; ++r) {
            int lr = tm2 * 16 + fq * 4 + r;
            int lc = tn * 16 + fr;
            ep[lr * 66 + lc] = fast_tanh(acc[tm][tn][r] + bv[tn]);
          }
        }
      }
#pragma unroll
      for (int p = 0; p < 2; ++p) {
        int lr = lane & 31;
        int ck = (lane >> 5) * 2 + p;
        int gm = m0 + wm * 64 + h * 32 + lr;
        int gc0 = n0 + wn * 64 + ck * 16;
#pragma unroll
        for (int q = 0; q < 4; ++q) {
          int col = gc0 + q * 4;
          if (col + 3 < SIG) {
            *(float4*)(out + (size_t)gm * SIG + col) =
                *(const float4*)&ep[lr * 66 + ck * 16 + q * 4];
          } else if (col < SIG) {
#pragma unroll
            for (int e = 0; e < 4; ++e) {
              int c2 = col + e;
              if (c2 < SIG) out[(size_t)gm * SIG + c2] = ep[lr * 66 + ck * 16 + q * 4 + e];
            }
          }
        }
      }
    }
    __syncthreads();  // epilogue LDS done before next nt's staging
  }
}

// ================= FALLBACK PATH (round-1, fp32) =============================
__global__ __launch_bounds__(256) void conv_kernel(
    const float* __restrict__ batch,
    const float* __restrict__ conv_w,
    const float* __restrict__ conv_b,
    float* __restrict__ b_out) {
  int idx = blockIdx.x * blockDim.x + threadIdx.x;
  if (idx >= N_B * T_LEN) return;
  int t = idx & (T_LEN - 1);
  const float* a = batch + (size_t)idx * IN_D;
  float a0 = a[0], a1 = a[1], a2 = a[2], a3 = a[3];
  float tm = (float)(t + 1) / (float)T_LEN;
  float* o = b_out + (size_t)idx * CH;
#pragma unroll
  for (int j = 0; j < CH; ++j) {
    const float* w = conv_w + j * CH;
    float r = conv_b[j];
    r = fmaf(tm, w[4], r);
    r = fmaf(a3, w[3], r);
    r = fmaf(a2, w[2], r);
    r = fmaf(a1, w[1], r);
    r = fmaf(a0, w[0], r);
    o[j] = r;
  }
}

__global__ __launch_bounds__(320) void sig_kernel_fb(
    const float* __restrict__ b_in, float* __restrict__ c_out) {
  int n = blockIdx.x;
  int tid = threadIdx.x;
  __shared__ float S[SIG];
  __shared__ float bc[64 * CH];
  __shared__ float dsh[CH];
  __shared__ float pb[CH];
  for (int i = tid; i < SIG; i += 320) S[i] = 0.0f;
  if (tid < CH) pb[tid] = 0.0f;
  const float* bn = b_in + (size_t)n * T_LEN * CH;
  float* cn = c_out + (size_t)n * T_LEN * SIG;
  const int x0 = tid, x1 = tid + 320;
  const bool has1 = (tid < 305);
  const int a0i = x0 / 125, b0i = (x0 / 25) % 5, c0i = (x0 / 5) % 5, d0i = x0 % 5;
  const int a1i = x1 / 125, b1i = (x1 / 25) % 5, c1i = (x1 / 5) % 5, d1i = x1 % 5;
  const int s2_0 = x0 / 25, s3_0 = x0 / 5, s2_1 = x1 / 25, s3_1 = x1 / 5;
  const bool hasL3 = (tid < 125);
  const int ya = tid / 25, yb = (tid / 5) % 5, yc = tid % 5;
  const bool hasL2 = (tid < 25);
  const int za = tid / 5, zb = tid % 5;
  const bool hasL1 = (tid < CH);
  for (int t = 0; t < T_LEN; ++t) {
    if ((t & 63) == 0) {
      __syncthreads();
      bc[tid] = bn[t * CH + tid];
      __syncthreads();
    }
    if (tid < CH) {
      float cur = bc[(t & 63) * CH + tid];
      dsh[tid] = cur - pb[tid];
      pb[tid] = cur;
    }
    __syncthreads();
    float n4_0, n4_1 = 0.0f, n3 = 0.0f, n2 = 0.0f, n1 = 0.0f;
    {
      float tH = fmaf(0.25f, dsh[a0i], S[a0i]);
      tH = fmaf((1.0f / 3.0f) * dsh[b0i], tH, S[5 + s2_0]);
      tH = fmaf(0.5f * dsh[c0i], tH, S[30 + s3_0]);
      n4_0 = fmaf(dsh[d0i], tH, S[155 + x0]);
    }
    if (has1) {
      float tH = fmaf(0.25f, dsh[a1i], S[a1i]);
      tH = fmaf((1.0f / 3.0f) * dsh[b1i], tH, S[5 + s2_1]);
      tH = fmaf(0.5f * dsh[c1i], tH, S[30 + s3_1]);
      n4_1 = fmaf(dsh[d1i], tH, S[155 + x1]);
    }
    if (hasL3) {
      float tH = fmaf((1.0f / 3.0f), dsh[ya], S[ya]);
      tH = fmaf(0.5f * dsh[yb], tH, S[5 + ya * 5 + yb]);
      n3 = fmaf(dsh[yc], tH, S[30 + tid]);
    }
    if (hasL2) {
      float tH = fmaf(0.5f, dsh[za], S[za]);
      n2 = fmaf(dsh[zb], tH, S[5 + tid]);
    }
    if (hasL1) n1 = S[tid] + dsh[tid];
    __syncthreads();
    S[155 + x0] = n4_0;
    if (has1) S[155 + x1] = n4_1;
    if (hasL3) S[30 + tid] = n3;
    if (hasL2) S[5 + tid] = n2;
    if (hasL1) S[tid] = n1;
    float* crow = cn + (size_t)t * SIG;
    float z = (t == 0) ? 0.0f : 1.0f;
    crow[155 + x0] = n4_0 * z;
    if (has1) crow[155 + x1] = n4_1 * z;
    if (hasL3) crow[30 + tid] = n3 * z;
    if (hasL2) crow[5 + tid] = n2 * z;
    if (hasL1) crow[tid] = n1 * z;
    __syncthreads();
  }
}

#define BM 256
#define BN 64
#define BK 16
__global__ __launch_bounds__(256) void gemm_tanh_fb(
    const float* __restrict__ Cmat, const float* __restrict__ W,
    const float* __restrict__ bias, float* __restrict__ out) {
  __shared__ float As[BK][BM + 4];
  __shared__ float Ws[BK][BN + 4];
  int tid = threadIdx.x;
  int tx = tid & 7, ty = tid >> 3;
  int m0 = blockIdx.x * BM, n0 = blockIdx.y * BN;
  float acc[8][8];
#pragma unroll
  for (int i = 0; i < 8; ++i)
#pragma unroll
    for (int j = 0; j < 8; ++j) acc[i][j] = 0.0f;
  for (int kb = 0; kb < SIG; kb += BK) {
    __syncthreads();
#pragma unroll
    for (int p = 0; p < 4; ++p) {
      int id = tid + p * 256;
      int row = id >> 2, kg = (id & 3) * 4, gk = kb + kg;
      float4 v = make_float4(0.f, 0.f, 0.f, 0.f);
      if (gk < SIG) v = *(const float4*)(Cmat + (size_t)(m0 + row) * SIG + gk);
      As[kg + 0][row] = v.x; As[kg + 1][row] = v.y;
      As[kg + 2][row] = v.z; As[kg + 3][row] = v.w;
    }
    {
      int row = tid >> 2, kg = (tid & 3) * 4, gk = kb + kg, wr = n0 + row;
      float4 v = make_float4(0.f, 0.f, 0.f, 0.f);
      if (gk < SIG && wr < SIG) v = *(const float4*)(W + (size_t)wr * SIG + gk);
      Ws[kg + 0][row] = v.x; Ws[kg + 1][row] = v.y;
      Ws[kg + 2][row] = v.z; Ws[kg + 3][row] = v.w;
    }
    __syncthreads();
#pragma unroll
    for (int k = 0; k < BK; ++k) {
      float af[8], wf[8];
      *(float4*)&af[0] = *(const float4*)&As[k][ty * 8];
      *(float4*)&af[4] = *(const float4*)&As[k][ty * 8 + 4];
      *(float4*)&wf[0] = *(const float4*)&Ws[k][tx * 8];
      *(float4*)&wf[4] = *(const float4*)&Ws[k][tx * 8 + 4];
#pragma unroll
      for (int i = 0; i < 8; ++i)
#pragma unroll
        for (int j = 0; j < 8; ++j) acc[i][j] = fmaf(af[i], wf[j], acc[i][j]);
    }
  }
#pragma unroll
  for (int i = 0; i < 8; ++i) {
    int m = m0 + ty * 8 + i;
    float* orow = out + (size_t)m * SIG;
#pragma unroll
    for (int jj = 0; jj < 8; jj += 4) {
      int col = n0 + tx * 8 + jj;
      if (col < SIG) {
        float4 r;
        r.x = tanhf(acc[i][jj + 0] + bias[col + 0]);
        r.y = tanhf(acc[i][jj + 1] + bias[col + 1]);
        r.z = tanhf(acc[i][jj + 2] + bias[col + 2]);
        r.w = tanhf(acc[i][jj + 3] + bias[col + 3]);
        *(float4*)(orow + col) = r;
      }
    }
  }
}

// ---------------- launch ----------------
extern "C" void kernel_launch(void* const* d_in, const int* in_sizes, int n_in,
                              void* d_out, int out_size, void* d_ws, size_t ws_size,
                              hipStream_t stream) {
  const float* batch = (const float*)d_in[0];
  const float* conv_w = (const float*)d_in[1];
  const float* conv_b = (const float*)d_in[2];
  const float* lin_w = (const float*)d_in[3];
  const float* lin_b = (const float*)d_in[4];
  float* out = (float*)d_out;

  const size_t plane_elems = (size_t)N_B * T_LEN * KP;        // 52,428,800
  const size_t wplane_elems = (size_t)NPAD * KP;              // 716,800
  const size_t P_elems = (size_t)N_B * N_SEG * SIG;           // 3,194,880
  const size_t bp_elems = (size_t)N_B * T_LEN * CH;
  const size_t need_big = 2 * plane_elems * sizeof(_Float16) +
                          2 * wplane_elems * sizeof(_Float16) +
                          P_elems * sizeof(float);

  if (ws_size >= need_big) {
    _Float16* c1 = (_Float16*)d_ws;
    _Float16* c2 = c1 + plane_elems;
    _Float16* w1 = c2 + plane_elems;
    _Float16* w2 = w1 + wplane_elems;
    float* P = (float*)(w2 + wplane_elems);

    wconv_kernel<<<dim3((NPAD * KP + 255) / 256), dim3(256), 0, stream>>>(
        lin_w, w1, w2);
    seg_wave<<<dim3(N_SEG, N_B), dim3(64), 0, stream>>>(batch, conv_w, conv_b, P);
    prefix_kernel<<<dim3(N_B), dim3(640), 0, stream>>>(P);
    emit_wave<<<dim3(N_SEG, N_B), dim3(64), 0, stream>>>(
        batch, conv_w, conv_b, P, c1, c2);
    gemm_mfma<<<dim3(512), dim3(256), 0, stream>>>(c1, c2, w1, w2, lin_b, out);
  } else {
    float* b_path = (float*)d_ws;
    float* c_sig = (float*)d_ws + bp_elems;
    conv_kernel<<<dim3((N_B * T_LEN + 255) / 256), dim3(256), 0, stream>>>(
        batch, conv_w, conv_b, b_path);
    sig_kernel_fb<<<dim3(N_B), dim3(320), 0, stream>>>(b_path, c_sig);
    gemm_tanh_fb<<<dim3((N_B * T_LEN) / BM, (SIG + BN - 1) / BN), dim3(256), 0, stream>>>(
        c_sig, lin_w, lin_b, out);
  }
}